// Round 4
// baseline (601.951 us; speedup 1.0000x reference)
//
#include <hip/hip_runtime.h>
#include <math.h>

// ---------------- workspace layout (float offsets) ----------------
#define NHEAD     10004
#define OFF_HEAD  0        // 10004 head logits
#define OFF_H0    10004    // 960 projected floats (h0|h1|h2|h3 contiguous)
#define OFF_C0    10964    // 10000 cluster-0 logits
#define OFF_C1    20964    // 20000
#define OFF_C2    40964    // 40000
#define OFF_C3    80964    // 20000
#define OFF_P     100964   // per-unit exp partials (NUNITS floats)
#define OFF_CNT   117348   // block-done ticket counter (int), zeroed by proj

// ---- uniform 8KB units: head 2 rows | c0 4 | c1 8 | c2 16 | c3 32 ----
// ALL exact divisions — no clamps anywhere.
#define B_C0   5002        // head units [0,5002):     5002*2  = 10004
#define B_C1   7502        // c0 units [5002,7502):    2500*4  = 10000
#define B_C2   10002       // c1 units [7502,10002):   2500*8  = 20000
#define B_C3   12502       // c2 units [10002,12502):  2500*16 = 40000
#define NUNITS 13127       // c3 units [12502,13127):  625*32  = 20000
#define NBLK   3282        // ceil(13127/4) waves/4 -> one unit per wave

__device__ __forceinline__ float wave_sum(float v) {
  v += __shfl_xor(v, 32, 64);
  v += __shfl_xor(v, 16, 64);
  v += __shfl_xor(v, 8, 64);
  v += __shfl_xor(v, 4, 64);
  v += __shfl_xor(v, 2, 64);
  v += __shfl_xor(v, 1, 64);
  return v;
}

__device__ __forceinline__ float dot4(float4 a, float4 c) {
  return a.x * c.x + a.y * c.y + a.z * c.z + a.w * c.w;
}

// Kernel A: 960 projection rows, 1 row/wave. Also zeroes the ticket counter.
__global__ __launch_bounds__(256) void proj_kernel(
    const float* __restrict__ feat,
    const float* __restrict__ p0, const float* __restrict__ p1,
    const float* __restrict__ p2, const float* __restrict__ p3,
    float* __restrict__ ws) {
  if (blockIdx.x == 0 && threadIdx.x == 0) ((int*)(ws + OFF_CNT))[0] = 0;
  __shared__ __align__(16) float sf[1024];
  ((float4*)sf)[threadIdx.x] = ((const float4*)feat)[threadIdx.x];
  __syncthreads();
  const float4* sf4 = (const float4*)sf;
  const int lane = threadIdx.x & 63;
  const int pr = blockIdx.x * 4 + (threadIdx.x >> 6);  // 0..959
  const float* src;
  if (pr < 512)      src = p0 + (size_t)pr * 1024;
  else if (pr < 768) src = p1 + (size_t)(pr - 512) * 1024;
  else if (pr < 896) src = p2 + (size_t)(pr - 768) * 1024;
  else               src = p3 + (size_t)(pr - 896) * 1024;
  const float4* src4 = (const float4*)src;
  float4 ld[4];
#pragma unroll
  for (int j = 0; j < 4; ++j) ld[j] = src4[lane + j * 64];
  float acc = 0.f;
#pragma unroll
  for (int j = 0; j < 4; ++j) acc += dot4(ld[j], sf4[lane + j * 64]);
  acc = wave_sum(acc);
  if (lane == 0) ws[NHEAD + pr] = acc;
}

// One uniform 8KB unit: 8 float4 loads per lane, loads and compute in ONE
// scope (never pass the array by pointer — r3's ping-pong got scratch-demoted
// to VGPR=48 and ran 3.6x slower). This is the r2-proven body.
__device__ __forceinline__ void process_unit(
    int u, int lane, const float* sh,
    const float* __restrict__ head_w, const float* __restrict__ w0,
    const float* __restrict__ w1, const float* __restrict__ w2,
    const float* __restrict__ w3, float* __restrict__ ws) {
  float esum = 0.f;
  if (u < B_C0) {                     // head: 2 rows, D=1024
    const float4* sf4 = (const float4*)sh;
    const int r0 = u * 2;
    const float4* w4 = (const float4*)head_w + (size_t)r0 * 256;
    float4 ld[8];
#pragma unroll
    for (int j = 0; j < 4; ++j) ld[j] = w4[lane + j * 64];
#pragma unroll
    for (int j = 0; j < 4; ++j) ld[4 + j] = w4[256 + lane + j * 64];
    float a0 = 0.f, a1 = 0.f;
#pragma unroll
    for (int j = 0; j < 4; ++j) {
      a0 += dot4(ld[j], sf4[lane + j * 64]);
      a1 += dot4(ld[4 + j], sf4[lane + j * 64]);
    }
    a0 = wave_sum(a0); a1 = wave_sum(a1);
    if (lane == 0) { ws[OFF_HEAD + r0] = a0; ws[OFF_HEAD + r0 + 1] = a1; }
    esum = expf(a0) + expf(a1);
  } else if (u < B_C1) {              // c0: 4 rows, h=512
    const float4* h4 = (const float4*)(sh + 1024);
    const float4 cv0 = h4[lane], cv1 = h4[lane + 64];
    const int r0 = (u - B_C0) * 4;
    const float4* w4 = (const float4*)w0 + (size_t)r0 * 128;
    float4 ld[8];
#pragma unroll
    for (int k = 0; k < 4; ++k) {
      ld[2 * k]     = w4[k * 128 + lane];
      ld[2 * k + 1] = w4[k * 128 + lane + 64];
    }
    float acc[4];
#pragma unroll
    for (int k = 0; k < 4; ++k)
      acc[k] = dot4(ld[2 * k], cv0) + dot4(ld[2 * k + 1], cv1);
#pragma unroll
    for (int k = 0; k < 4; ++k) {
      float a = wave_sum(acc[k]);
      if (lane == 0) ws[OFF_C0 + r0 + k] = a;
      esum += expf(a);
    }
  } else if (u < B_C2) {              // c1: 8 rows, h=256
    const float4 cv = ((const float4*)(sh + 1536))[lane];
    const int r0 = (u - B_C1) * 8;
    float4 ld[8];
#pragma unroll
    for (int k = 0; k < 8; ++k)
      ld[k] = ((const float4*)w1)[(size_t)(r0 + k) * 64 + lane];
    float acc[8];
#pragma unroll
    for (int k = 0; k < 8; ++k) acc[k] = dot4(ld[k], cv);
#pragma unroll
    for (int k = 0; k < 8; ++k) {
      float a = wave_sum(acc[k]);
      if (lane == 0) ws[OFF_C1 + r0 + k] = a;
      esum += expf(a);
    }
  } else if (u < B_C3) {              // c2: 16 rows, h=128, 2 rows/wave-load
    const float4 cv = ((const float4*)(sh + 1792))[lane & 31];
    const int r0 = (u - B_C2) * 16;
    float4 ld[8];
#pragma unroll
    for (int p = 0; p < 8; ++p)
      ld[p] = ((const float4*)w2)[(size_t)(r0 + 2 * p) * 32 + lane];
#pragma unroll
    for (int p = 0; p < 8; ++p) {
      float a = dot4(ld[p], cv);
      a += __shfl_xor(a, 1, 64);
      a += __shfl_xor(a, 2, 64);
      a += __shfl_xor(a, 4, 64);
      a += __shfl_xor(a, 8, 64);
      a += __shfl_xor(a, 16, 64);     // each 32-half holds its row sum
      if ((lane & 31) == 0) ws[OFF_C2 + r0 + 2 * p + (lane >> 5)] = a;
      esum += expf(a);                // per-lane: its half's 8 rows
    }
    esum += __shfl_xor(esum, 32, 64); // combine the two halves
  } else {                            // c3: 32 rows, h=64, 4 rows/wave-load
    const float4 cv = ((const float4*)(sh + 1920))[lane & 15];
    const int r0 = (u - B_C3) * 32;
    float4 ld[8];
#pragma unroll
    for (int p = 0; p < 8; ++p)
      ld[p] = ((const float4*)w3)[(size_t)(r0 + 4 * p) * 16 + lane];
#pragma unroll
    for (int p = 0; p < 8; ++p) {
      float a = dot4(ld[p], cv);
      a += __shfl_xor(a, 1, 64);
      a += __shfl_xor(a, 2, 64);
      a += __shfl_xor(a, 4, 64);
      a += __shfl_xor(a, 8, 64);      // each 16-group holds its row sum
      if ((lane & 15) == 0) ws[OFF_C3 + r0 + 4 * p + (lane >> 4)] = a;
      esum += expf(a);                // per-lane: its quarter's 8 rows
    }
    esum += __shfl_xor(esum, 16, 64);
    esum += __shfl_xor(esum, 32, 64); // combine the four quarters
  }
  if (lane == 0) ws[OFF_P + u] = esum;
}

// Kernel B: 3282 blocks, one 8KB unit per wave (r2-proven structure), plus
// fused last-block finalize (ticket pattern, r3-proven correct).
__global__ __launch_bounds__(256, 4) void main_kernel(
    const float* __restrict__ feat, const float* __restrict__ head_w,
    const float* __restrict__ w0, const float* __restrict__ w1,
    const float* __restrict__ w2, const float* __restrict__ w3,
    const int* __restrict__ targets, float* __restrict__ ws,
    float* __restrict__ out) {
  __shared__ __align__(16) float sh[1984];  // feat[1024] | proj[960]
  __shared__ float r5[4][5];
  __shared__ float slse[5];
  __shared__ int isLast;
  const int t = threadIdx.x;
  ((float4*)sh)[t] = ((const float4*)feat)[t];
  if (t < 240) ((float4*)(sh + 1024))[t] = ((const float4*)(ws + OFF_H0))[t];
  __syncthreads();
  const int lane = t & 63;
  const int u = blockIdx.x * 4 + (t >> 6);
  if (u < NUNITS)
    process_unit(u, lane, sh, head_w, w0, w1, w2, w3, ws);

  // ---- ticket: release our stores, count this block done ----
  __threadfence();
  __syncthreads();
  if (t == 0) {
    int old = atomicAdd((int*)(ws + OFF_CNT), 1);
    isLast = (old == NBLK - 1);
  }
  __syncthreads();
  if (!isLast) return;
  __threadfence();  // acquire: all blocks' stores now visible

  // ---- fused finalize (256 threads) ----
  const int wv = t >> 6;
  float a0 = 0.f, a1 = 0.f, a2 = 0.f, a3 = 0.f, a4 = 0.f;
#pragma unroll 4
  for (int it = 0; it < 52; ++it) {
    int i = t + it * 256;
    if (i < NUNITS) {
      float v = ws[OFF_P + i];
      if (i < B_C0)      a0 += v;
      else if (i < B_C1) a1 += v;
      else if (i < B_C2) a2 += v;
      else if (i < B_C3) a3 += v;
      else               a4 += v;
    }
  }
  a0 = wave_sum(a0); a1 = wave_sum(a1); a2 = wave_sum(a2);
  a3 = wave_sum(a3); a4 = wave_sum(a4);
  if (lane == 0) { r5[wv][0] = a0; r5[wv][1] = a1; r5[wv][2] = a2; r5[wv][3] = a3; r5[wv][4] = a4; }
  __syncthreads();
  if (t < 5) {
    slse[t] = logf(r5[0][t] + r5[1][t] + r5[2][t] + r5[3][t]);
  }
  __syncthreads();
  const float lse0 = slse[0], lse1 = slse[1], lse2 = slse[2], lse3 = slse[3], lse4 = slse[4];
  const float g0 = ws[10000] - lse0, g1 = ws[10001] - lse0;
  const float g2 = ws[10002] - lse0, g3 = ws[10003] - lse0;
  float s = 0.f;
#pragma unroll 4
  for (int it = 0; it < 16; ++it) {
    int tgt = targets[t + it * 256];
    int addr = tgt + ((tgt >= 10000) ? 964 : 0);   // layout: all clusters at +964
    float lp = ws[addr];
    int e = (tgt >= 10000) + (tgt >= 20000) + (tgt >= 40000) + (tgt >= 80000);
    float lseS = (e == 0) ? lse0 : (e == 1) ? lse1 : (e == 2) ? lse2 : (e == 3) ? lse3 : lse4;
    float gS   = (e == 0) ? 0.f  : (e == 1) ? g0   : (e == 2) ? g1   : (e == 3) ? g2   : g3;
    s += lp - lseS + gS;
  }
  s = wave_sum(s);
  if (lane == 0) r5[wv][0] = s;
  __syncthreads();
  if (t == 0)
    out[0] = -(r5[0][0] + r5[1][0] + r5[2][0] + r5[3][0]) * (1.f / 4096.f);
}

extern "C" void kernel_launch(void* const* d_in, const int* in_sizes, int n_in,
                              void* d_out, int out_size, void* d_ws, size_t ws_size,
                              hipStream_t stream) {
  const float* feat    = (const float*)d_in[0];
  const int*   targets = (const int*)d_in[1];
  const float* head_w  = (const float*)d_in[2];
  const float* t0p = (const float*)d_in[3];
  const float* t0w = (const float*)d_in[4];
  const float* t1p = (const float*)d_in[5];
  const float* t1w = (const float*)d_in[6];
  const float* t2p = (const float*)d_in[7];
  const float* t2w = (const float*)d_in[8];
  const float* t3p = (const float*)d_in[9];
  const float* t3w = (const float*)d_in[10];
  float* ws  = (float*)d_ws;
  float* out = (float*)d_out;

  proj_kernel<<<240, 256, 0, stream>>>(feat, t0p, t1p, t2p, t3p, ws);
  main_kernel<<<NBLK, 256, 0, stream>>>(feat, head_w, t0w, t1w, t2w, t3w,
                                        targets, ws, out);
}

// Round 5
// 160.646 us; speedup vs baseline: 3.7471x; 3.7471x over previous
//
#include <hip/hip_runtime.h>
#include <math.h>

// ---------------- workspace layout (float offsets) ----------------
#define NHEAD     10004
#define OFF_HEAD  0        // 10004 head logits
#define OFF_H0    10004    // 960 projected floats (h0|h1|h2|h3 contiguous)
#define OFF_C0    10964    // 10000 cluster-0 logits
#define OFF_C1    20964    // 20000
#define OFF_C2    40964    // 40000
#define OFF_C3    80964    // 20000
#define OFF_P     100964   // per-pair exp partials (NPAIR floats)

// ---- paired 16KB units (2x8KB, contiguous, never cross a segment since all
// segment boundaries are even). Pair w covers units {2w, 2w+1}.
// head pairs [0,2501):    2501*4  = 10004 rows exact
// c0   pairs [2501,3751): 1250*8  = 10000 exact
// c1   pairs [3751,5001): 1250*16 = 20000 exact
// c2   pairs [5001,6251): 1250*32 = 40000 exact
// c3   pairs [6251,6564): 313*64  = 20032 (last pair half-valid)
#define P_C0   2501
#define P_C1   3751
#define P_C2   5001
#define P_C3   6251
#define NPAIR  6564
#define NBLK   1641        // 1641*4 = 6564 waves, one pair per wave

__device__ __forceinline__ float wave_sum(float v) {
  v += __shfl_xor(v, 32, 64);
  v += __shfl_xor(v, 16, 64);
  v += __shfl_xor(v, 8, 64);
  v += __shfl_xor(v, 4, 64);
  v += __shfl_xor(v, 2, 64);
  v += __shfl_xor(v, 1, 64);
  return v;
}

__device__ __forceinline__ float dot4(float4 a, float4 c) {
  return a.x * c.x + a.y * c.y + a.z * c.z + a.w * c.w;
}

// Kernel A: 960 projection rows, 1 row/wave.
__global__ __launch_bounds__(256) void proj_kernel(
    const float* __restrict__ feat,
    const float* __restrict__ p0, const float* __restrict__ p1,
    const float* __restrict__ p2, const float* __restrict__ p3,
    float* __restrict__ ws) {
  __shared__ __align__(16) float sf[1024];
  ((float4*)sf)[threadIdx.x] = ((const float4*)feat)[threadIdx.x];
  __syncthreads();
  const float4* sf4 = (const float4*)sf;
  const int lane = threadIdx.x & 63;
  const int pr = blockIdx.x * 4 + (threadIdx.x >> 6);  // 0..959
  const float* src;
  if (pr < 512)      src = p0 + (size_t)pr * 1024;
  else if (pr < 768) src = p1 + (size_t)(pr - 512) * 1024;
  else if (pr < 896) src = p2 + (size_t)(pr - 768) * 1024;
  else               src = p3 + (size_t)(pr - 896) * 1024;
  const float4* src4 = (const float4*)src;
  float4 ld[4];
#pragma unroll
  for (int j = 0; j < 4; ++j) ld[j] = src4[lane + j * 64];
  float acc = 0.f;
#pragma unroll
  for (int j = 0; j < 4; ++j) acc += dot4(ld[j], sf4[lane + j * 64]);
  acc = wave_sum(acc);
  if (lane == 0) ws[NHEAD + pr] = acc;
}

// Kernel B: 1641 blocks, one contiguous 16KB pair per wave. No atomics, no
// fences (r3/r4: same-address ticket atomics serialize at ~150ns each —
// 3282 blocks = +490us). ld[16] declared per-branch, straight-line,
// constant-indexed; (256,3) caps occupancy target so the allocator keeps
// all 64 data VGPRs live (r1's squeeze came from an unbounded target).
__global__ __launch_bounds__(256, 3) void main_kernel(
    const float* __restrict__ feat, const float* __restrict__ head_w,
    const float* __restrict__ w0, const float* __restrict__ w1,
    const float* __restrict__ w2, const float* __restrict__ w3,
    float* __restrict__ ws) {
  __shared__ __align__(16) float sh[1984];  // feat[1024] | proj[960]
  const int t = threadIdx.x;
  ((float4*)sh)[t] = ((const float4*)feat)[t];
  if (t < 240) ((float4*)(sh + 1024))[t] = ((const float4*)(ws + OFF_H0))[t];
  __syncthreads();
  const int lane = t & 63;
  const int w = blockIdx.x * 4 + (t >> 6);  // pair id, 0..6563
  float esum = 0.f;

  if (w < P_C0) {                     // head: 4 rows, D=1024
    const float4* sf4 = (const float4*)sh;
    const float4* base = (const float4*)head_w + (size_t)w * 1024;
    float4 ld[16];
#pragma unroll
    for (int j = 0; j < 16; ++j) ld[j] = base[j * 64 + lane];
    float a[4];
#pragma unroll
    for (int k = 0; k < 4; ++k) {
      float s = 0.f;
#pragma unroll
      for (int j = 0; j < 4; ++j) s += dot4(ld[4 * k + j], sf4[lane + j * 64]);
      a[k] = s;
    }
    const int r0 = w * 4;
#pragma unroll
    for (int k = 0; k < 4; ++k) {
      float s = wave_sum(a[k]);
      if (lane == 0) ws[OFF_HEAD + r0 + k] = s;
      esum += expf(s);
    }
  } else if (w < P_C1) {              // c0: 8 rows, h=512
    const float4* h4 = (const float4*)(sh + 1024);
    const float4 cv0 = h4[lane], cv1 = h4[lane + 64];
    const int v = w - P_C0, r0 = v * 8;
    const float4* base = (const float4*)w0 + (size_t)v * 1024;
    float4 ld[16];
#pragma unroll
    for (int j = 0; j < 16; ++j) ld[j] = base[j * 64 + lane];
#pragma unroll
    for (int k = 0; k < 8; ++k) {
      float a = dot4(ld[2 * k], cv0) + dot4(ld[2 * k + 1], cv1);
      a = wave_sum(a);
      if (lane == 0) ws[OFF_C0 + r0 + k] = a;
      esum += expf(a);
    }
  } else if (w < P_C2) {              // c1: 16 rows, h=256
    const float4 cv = ((const float4*)(sh + 1536))[lane];
    const int v = w - P_C1, r0 = v * 16;
    const float4* base = (const float4*)w1 + (size_t)v * 1024;
    float4 ld[16];
#pragma unroll
    for (int j = 0; j < 16; ++j) ld[j] = base[j * 64 + lane];
#pragma unroll
    for (int k = 0; k < 16; ++k) {
      float a = wave_sum(dot4(ld[k], cv));
      if (lane == 0) ws[OFF_C1 + r0 + k] = a;
      esum += expf(a);
    }
  } else if (w < P_C3) {              // c2: 32 rows, h=128, 2 rows/wave-load
    const float4 cv = ((const float4*)(sh + 1792))[lane & 31];
    const int v = w - P_C2, r0 = v * 32;
    const float4* base = (const float4*)w2 + (size_t)v * 1024;
    float4 ld[16];
#pragma unroll
    for (int j = 0; j < 16; ++j) ld[j] = base[j * 64 + lane];
#pragma unroll
    for (int p = 0; p < 16; ++p) {
      float a = dot4(ld[p], cv);
      a += __shfl_xor(a, 1, 64);
      a += __shfl_xor(a, 2, 64);
      a += __shfl_xor(a, 4, 64);
      a += __shfl_xor(a, 8, 64);
      a += __shfl_xor(a, 16, 64);     // each 32-half holds its row sum
      if ((lane & 31) == 0) ws[OFF_C2 + r0 + 2 * p + (lane >> 5)] = a;
      esum += expf(a);                // per-lane: its half's 16 rows
    }
    esum += __shfl_xor(esum, 32, 64); // combine the two halves
  } else {                            // c3: 64 rows, h=64, 4 rows/wave-load
    const float4 cv = ((const float4*)(sh + 1920))[lane & 15];
    const int v = w - P_C3, r0 = v * 64;
    const float4* base = (const float4*)w3 + (size_t)v * 1024;
    const bool full = (r0 + 64) <= 20000;          // wave-uniform; only last pair false
    const float4* base2 = full ? base + 512 : base; // clamp OOB half (reload, discard)
    float4 ld[16];
#pragma unroll
    for (int j = 0; j < 8; ++j) ld[j] = base[j * 64 + lane];
#pragma unroll
    for (int j = 0; j < 8; ++j) ld[8 + j] = base2[j * 64 + lane];
#pragma unroll
    for (int p = 0; p < 8; ++p) {     // first unit: rows r0..r0+31, always valid
      float a = dot4(ld[p], cv);
      a += __shfl_xor(a, 1, 64);
      a += __shfl_xor(a, 2, 64);
      a += __shfl_xor(a, 4, 64);
      a += __shfl_xor(a, 8, 64);      // each 16-group holds its row sum
      if ((lane & 15) == 0) ws[OFF_C3 + r0 + 4 * p + (lane >> 4)] = a;
      esum += expf(a);
    }
    if (full) {
#pragma unroll
      for (int p = 0; p < 8; ++p) {   // second unit: rows r0+32..r0+63
        float a = dot4(ld[8 + p], cv);
        a += __shfl_xor(a, 1, 64);
        a += __shfl_xor(a, 2, 64);
        a += __shfl_xor(a, 4, 64);
        a += __shfl_xor(a, 8, 64);
        if ((lane & 15) == 0) ws[OFF_C3 + r0 + 32 + 4 * p + (lane >> 4)] = a;
        esum += expf(a);
      }
    }
    esum += __shfl_xor(esum, 16, 64);
    esum += __shfl_xor(esum, 32, 64); // combine the four quarters
  }
  if (lane == 0) ws[OFF_P + w] = esum;
}

// Kernel C: single 1024-thread block. Gathers issued branchlessly at entry
// (addr = t + (t>=10000)*964 by layout), overlapping the partial reduction.
__global__ __launch_bounds__(1024) void finalize_kernel(
    const int* __restrict__ targets, float* __restrict__ ws,
    float* __restrict__ out) {
  const int tid = threadIdx.x;
  const int wv = tid >> 6, lane = tid & 63;
  float tv[4]; int sg[4];
#pragma unroll
  for (int it = 0; it < 4; ++it) {
    int tgt = targets[tid + it * 1024];
    int addr = tgt + ((tgt >= 10000) ? 964 : 0);
    tv[it] = ws[addr];
    sg[it] = (tgt >= 10000) + (tgt >= 20000) + (tgt >= 40000) + (tgt >= 80000);
  }
  // segmented reduction of 6564 per-pair partials
  float a0 = 0.f, a1 = 0.f, a2 = 0.f, a3 = 0.f, a4 = 0.f;
#pragma unroll
  for (int it = 0; it < 7; ++it) {
    int i = tid + it * 1024;
    if (i < NPAIR) {
      float v = ws[OFF_P + i];
      if (i < P_C0)      a0 += v;
      else if (i < P_C1) a1 += v;
      else if (i < P_C2) a2 += v;
      else if (i < P_C3) a3 += v;
      else               a4 += v;
    }
  }
  a0 = wave_sum(a0); a1 = wave_sum(a1); a2 = wave_sum(a2);
  a3 = wave_sum(a3); a4 = wave_sum(a4);
  __shared__ float r5[16][5];
  __shared__ float slse[5];
  if (lane == 0) { r5[wv][0] = a0; r5[wv][1] = a1; r5[wv][2] = a2; r5[wv][3] = a3; r5[wv][4] = a4; }
  __syncthreads();
  if (tid < 5) {
    float s = 0.f;
#pragma unroll
    for (int w = 0; w < 16; ++w) s += r5[w][tid];
    slse[tid] = logf(s);
  }
  __syncthreads();
  const float lse0 = slse[0], lse1 = slse[1], lse2 = slse[2], lse3 = slse[3], lse4 = slse[4];
  const float g0 = ws[10000] - lse0, g1 = ws[10001] - lse0;
  const float g2 = ws[10002] - lse0, g3 = ws[10003] - lse0;
  float s = 0.f;
#pragma unroll
  for (int it = 0; it < 4; ++it) {
    int e = sg[it];
    float lseS = (e == 0) ? lse0 : (e == 1) ? lse1 : (e == 2) ? lse2 : (e == 3) ? lse3 : lse4;
    float gS   = (e == 0) ? 0.f  : (e == 1) ? g0   : (e == 2) ? g1   : (e == 3) ? g2   : g3;
    s += tv[it] - lseS + gS;
  }
  s = wave_sum(s);
  if (lane == 0) r5[wv][0] = s;
  __syncthreads();
  if (tid == 0) {
    float tot = 0.f;
#pragma unroll
    for (int w = 0; w < 16; ++w) tot += r5[w][0];
    out[0] = -tot * (1.f / 4096.f);
  }
}

extern "C" void kernel_launch(void* const* d_in, const int* in_sizes, int n_in,
                              void* d_out, int out_size, void* d_ws, size_t ws_size,
                              hipStream_t stream) {
  const float* feat    = (const float*)d_in[0];
  const int*   targets = (const int*)d_in[1];
  const float* head_w  = (const float*)d_in[2];
  const float* t0p = (const float*)d_in[3];
  const float* t0w = (const float*)d_in[4];
  const float* t1p = (const float*)d_in[5];
  const float* t1w = (const float*)d_in[6];
  const float* t2p = (const float*)d_in[7];
  const float* t2w = (const float*)d_in[8];
  const float* t3p = (const float*)d_in[9];
  const float* t3w = (const float*)d_in[10];
  float* ws  = (float*)d_ws;
  float* out = (float*)d_out;

  proj_kernel<<<240, 256, 0, stream>>>(feat, t0p, t1p, t2p, t3p, ws);
  main_kernel<<<NBLK, 256, 0, stream>>>(feat, head_w, t0w, t1w, t2w, t3w, ws);
  finalize_kernel<<<1, 1024, 0, stream>>>(targets, ws, out);
}

// Round 6
// 157.786 us; speedup vs baseline: 3.8150x; 1.0181x over previous
//
#include <hip/hip_runtime.h>
#include <math.h>

// ---------------- workspace layout (float offsets) ----------------
#define NHEAD     10004
#define OFF_HEAD  0        // 10004 head logits
#define OFF_H0    10004    // 960 projected floats (h0|h1|h2|h3 contiguous)
#define OFF_C0    10964    // 10000 cluster-0 logits
#define OFF_C1    20964    // 20000
#define OFF_C2    40964    // 40000
#define OFF_C3    80964    // 20000
#define OFF_P     100964   // per-pair exp partials (NPAIR floats)

// ---- paired 16KB units (contiguous, never cross a segment) ----
// head pairs [0,2501):    2501*4  = 10004 rows exact
// c0   pairs [2501,3751): 1250*8  = 10000 exact
// c1   pairs [3751,5001): 1250*16 = 20000 exact
// c2   pairs [5001,6251): 1250*32 = 40000 exact
// c3   pairs [6251,6564): 313*64  = 20032 (last pair half-valid)
#define P_C0   2501
#define P_C1   3751
#define P_C2   5001
#define P_C3   6251
#define NPAIR  6564
#define NBLK   1641        // 1641*4 = 6564 waves, one pair per wave

__device__ __forceinline__ float wave_sum(float v) {
  v += __shfl_xor(v, 32, 64);
  v += __shfl_xor(v, 16, 64);
  v += __shfl_xor(v, 8, 64);
  v += __shfl_xor(v, 4, 64);
  v += __shfl_xor(v, 2, 64);
  v += __shfl_xor(v, 1, 64);
  return v;
}

__device__ __forceinline__ float dot4(float4 a, float4 c) {
  return a.x * c.x + a.y * c.y + a.z * c.z + a.w * c.w;
}

// Merge two row-partials across xor-distance s: lanes with (lane&s)==0 keep
// a's row (now spanning 2x lanes), lanes with bit set keep b's row. Row-index
// bits accumulate into lane-index bits.
__device__ __forceinline__ float mrg(float a, float b, int s, int lane) {
  float as = __shfl_xor(a, s, 64);
  float bs = __shfl_xor(b, s, 64);
  return (lane & s) ? (b + bs) : (a + as);
}

// Kernel A: 960 projection rows, 1 row/wave.
__global__ __launch_bounds__(256) void proj_kernel(
    const float* __restrict__ feat,
    const float* __restrict__ p0, const float* __restrict__ p1,
    const float* __restrict__ p2, const float* __restrict__ p3,
    float* __restrict__ ws) {
  __shared__ __align__(16) float sf[1024];
  ((float4*)sf)[threadIdx.x] = ((const float4*)feat)[threadIdx.x];
  __syncthreads();
  const float4* sf4 = (const float4*)sf;
  const int lane = threadIdx.x & 63;
  const int pr = blockIdx.x * 4 + (threadIdx.x >> 6);  // 0..959
  const float* src;
  if (pr < 512)      src = p0 + (size_t)pr * 1024;
  else if (pr < 768) src = p1 + (size_t)(pr - 512) * 1024;
  else if (pr < 896) src = p2 + (size_t)(pr - 768) * 1024;
  else               src = p3 + (size_t)(pr - 896) * 1024;
  const float4* src4 = (const float4*)src;
  float4 ld[4];
#pragma unroll
  for (int j = 0; j < 4; ++j) ld[j] = src4[lane + j * 64];
  float acc = 0.f;
#pragma unroll
  for (int j = 0; j < 4; ++j) acc += dot4(ld[j], sf4[lane + j * 64]);
  acc = wave_sum(acc);
  if (lane == 0) ws[NHEAD + pr] = acc;
}

// Kernel B: 1641 blocks, one contiguous 16KB pair per wave. Row reductions
// use merge-trees (rows distributed onto lane bits): ~3x fewer DS ops and
// chain depth ~10 levels per pair instead of 6-deep chains PER ROW — the
// dependent-shuffle latency was the invariant stall across r0/r2/r5.
__global__ __launch_bounds__(256, 3) void main_kernel(
    const float* __restrict__ feat, const float* __restrict__ head_w,
    const float* __restrict__ w0, const float* __restrict__ w1,
    const float* __restrict__ w2, const float* __restrict__ w3,
    float* __restrict__ ws) {
  __shared__ __align__(16) float sh[1984];  // feat[1024] | proj[960]
  const int t = threadIdx.x;
  ((float4*)sh)[t] = ((const float4*)feat)[t];
  if (t < 240) ((float4*)(sh + 1024))[t] = ((const float4*)(ws + OFF_H0))[t];
  __syncthreads();
  const int lane = t & 63;
  const int w = blockIdx.x * 4 + (t >> 6);  // pair id, 0..6563
  float esum;

  if (w < P_C0) {                     // head: 4 rows, D=1024
    const float4* sf4 = (const float4*)sh;
    const float4* base = (const float4*)head_w + (size_t)w * 1024;
    float4 ld[16];
#pragma unroll
    for (int j = 0; j < 16; ++j) ld[j] = base[j * 64 + lane];
    float a[4];
#pragma unroll
    for (int k = 0; k < 4; ++k) {
      float s = 0.f;
#pragma unroll
      for (int j = 0; j < 4; ++j) s += dot4(ld[4 * k + j], sf4[lane + j * 64]);
      a[k] = s;
    }
    // merge-tree: row = lane&3 after 2 stages, then finish 4 stages
    float u0 = mrg(a[0], a[1], 1, lane), u1 = mrg(a[2], a[3], 1, lane);
    float y = mrg(u0, u1, 2, lane);
    y += __shfl_xor(y, 4, 64);
    y += __shfl_xor(y, 8, 64);
    y += __shfl_xor(y, 16, 64);
    y += __shfl_xor(y, 32, 64);
    if (lane < 4) ws[OFF_HEAD + w * 4 + lane] = y;
    float ev = expf(y);                 // rows on lane bits 0-1 (16 dups)
    ev += __shfl_xor(ev, 1, 64);
    ev += __shfl_xor(ev, 2, 64);
    esum = ev;
  } else if (w < P_C1) {              // c0: 8 rows, h=512
    const float4* h4 = (const float4*)(sh + 1024);
    const float4 cv0 = h4[lane], cv1 = h4[lane + 64];
    const int v = w - P_C0, r0 = v * 8;
    const float4* base = (const float4*)w0 + (size_t)v * 1024;
    float4 ld[16];
#pragma unroll
    for (int j = 0; j < 16; ++j) ld[j] = base[j * 64 + lane];
    float a[8];
#pragma unroll
    for (int k = 0; k < 8; ++k)
      a[k] = dot4(ld[2 * k], cv0) + dot4(ld[2 * k + 1], cv1);
    float u[4];
#pragma unroll
    for (int m = 0; m < 4; ++m) u[m] = mrg(a[2 * m], a[2 * m + 1], 1, lane);
    float v0 = mrg(u[0], u[1], 2, lane), v1 = mrg(u[2], u[3], 2, lane);
    float y = mrg(v0, v1, 4, lane);     // row = lane&7
    y += __shfl_xor(y, 8, 64);
    y += __shfl_xor(y, 16, 64);
    y += __shfl_xor(y, 32, 64);
    if (lane < 8) ws[OFF_C0 + r0 + lane] = y;
    float ev = expf(y);                 // rows on lane bits 0-2 (8 dups)
    ev += __shfl_xor(ev, 1, 64);
    ev += __shfl_xor(ev, 2, 64);
    ev += __shfl_xor(ev, 4, 64);
    esum = ev;
  } else if (w < P_C2) {              // c1: 16 rows, h=256
    const float4 cv = ((const float4*)(sh + 1536))[lane];
    const int v = w - P_C1, r0 = v * 16;
    const float4* base = (const float4*)w1 + (size_t)v * 1024;
    float4 ld[16];
#pragma unroll
    for (int j = 0; j < 16; ++j) ld[j] = base[j * 64 + lane];
    float a[16];
#pragma unroll
    for (int k = 0; k < 16; ++k) a[k] = dot4(ld[k], cv);
    float u[8];
#pragma unroll
    for (int m = 0; m < 8; ++m) u[m] = mrg(a[2 * m], a[2 * m + 1], 1, lane);
    float v2[4];
#pragma unroll
    for (int m = 0; m < 4; ++m) v2[m] = mrg(u[2 * m], u[2 * m + 1], 2, lane);
    float w2r[2];
#pragma unroll
    for (int m = 0; m < 2; ++m) w2r[m] = mrg(v2[2 * m], v2[2 * m + 1], 4, lane);
    float y = mrg(w2r[0], w2r[1], 8, lane);  // row = lane&15
    y += __shfl_xor(y, 16, 64);
    y += __shfl_xor(y, 32, 64);
    if (lane < 16) ws[OFF_C1 + r0 + lane] = y;
    float ev = expf(y);                 // rows on lane bits 0-3 (4 dups)
    ev += __shfl_xor(ev, 1, 64);
    ev += __shfl_xor(ev, 2, 64);
    ev += __shfl_xor(ev, 4, 64);
    ev += __shfl_xor(ev, 8, 64);
    esum = ev;
  } else if (w < P_C3) {              // c2: 32 rows, h=128 (32 lanes/row)
    const float4 cv = ((const float4*)(sh + 1792))[lane & 31];
    const int v = w - P_C2, r0 = v * 32;
    const float4* base = (const float4*)w2 + (size_t)v * 1024;
    float4 ld[16];
#pragma unroll
    for (int j = 0; j < 16; ++j) ld[j] = base[j * 64 + lane];
    float a[16];                        // a[p]: row 2p + (lane>=32), pos lane&31
#pragma unroll
    for (int p = 0; p < 16; ++p) a[p] = dot4(ld[p], cv);
    float u[8];
#pragma unroll
    for (int m = 0; m < 8; ++m) u[m] = mrg(a[2 * m], a[2 * m + 1], 1, lane);
    float v2[4];
#pragma unroll
    for (int m = 0; m < 4; ++m) v2[m] = mrg(u[2 * m], u[2 * m + 1], 2, lane);
    float w2r[2];
#pragma unroll
    for (int m = 0; m < 2; ++m) w2r[m] = mrg(v2[2 * m], v2[2 * m + 1], 4, lane);
    float y = mrg(w2r[0], w2r[1], 8, lane);  // p = lane&15
    y += __shfl_xor(y, 16, 64);         // complete 32-lane row sum (dup at ^16)
    int rr = 2 * (lane & 15) + (lane >> 5);  // row in [0,32)
    if (!(lane & 16)) ws[OFF_C2 + r0 + rr] = y;
    float ev = expf(y);                 // rows on lane bits 0-3 and 5 (2 dups)
    ev += __shfl_xor(ev, 1, 64);
    ev += __shfl_xor(ev, 2, 64);
    ev += __shfl_xor(ev, 4, 64);
    ev += __shfl_xor(ev, 8, 64);
    ev += __shfl_xor(ev, 32, 64);
    esum = ev;
  } else {                            // c3: 64 rows, h=64 (16 lanes/row)
    const float4 cv = ((const float4*)(sh + 1920))[lane & 15];
    const int v = w - P_C3, r0 = v * 64;
    const float4* base = (const float4*)w3 + (size_t)v * 1024;
    const bool full = (r0 + 64) <= 20000;           // only last pair false
    const float4* base2 = full ? base + 512 : base;  // clamp OOB half
    float4 ld[16];
#pragma unroll
    for (int j = 0; j < 8; ++j) ld[j] = base[j * 64 + lane];
#pragma unroll
    for (int j = 0; j < 8; ++j) ld[8 + j] = base2[j * 64 + lane];
    float a[16];                        // a[p]: row 4p + (lane>>4), pos lane&15
#pragma unroll
    for (int p = 0; p < 16; ++p) a[p] = dot4(ld[p], cv);
    float u[8];
#pragma unroll
    for (int m = 0; m < 8; ++m) u[m] = mrg(a[2 * m], a[2 * m + 1], 1, lane);
    float v2[4];
#pragma unroll
    for (int m = 0; m < 4; ++m) v2[m] = mrg(u[2 * m], u[2 * m + 1], 2, lane);
    float w2r[2];
#pragma unroll
    for (int m = 0; m < 2; ++m) w2r[m] = mrg(v2[2 * m], v2[2 * m + 1], 4, lane);
    float y = mrg(w2r[0], w2r[1], 8, lane);  // full row sum; p = lane&15
    int rr = 4 * (lane & 15) + (lane >> 4);  // row in [0,64); all lanes distinct
    bool valid = (r0 + rr) < 20000;
    if (valid) ws[OFF_C3 + r0 + rr] = y;
    float ev = valid ? expf(y) : 0.f;
    esum = wave_sum(ev);                // 64 distinct rows
  }
  if (lane == 0) ws[OFF_P + w] = esum;
}

// Kernel C: single 1024-thread block. Gathers issued branchlessly at entry
// (addr = t + (t>=10000)*964 by layout), overlapping the partial reduction.
__global__ __launch_bounds__(1024) void finalize_kernel(
    const int* __restrict__ targets, float* __restrict__ ws,
    float* __restrict__ out) {
  const int tid = threadIdx.x;
  const int wv = tid >> 6, lane = tid & 63;
  float tv[4]; int sg[4];
#pragma unroll
  for (int it = 0; it < 4; ++it) {
    int tgt = targets[tid + it * 1024];
    int addr = tgt + ((tgt >= 10000) ? 964 : 0);
    tv[it] = ws[addr];
    sg[it] = (tgt >= 10000) + (tgt >= 20000) + (tgt >= 40000) + (tgt >= 80000);
  }
  // segmented reduction of 6564 per-pair partials
  float a0 = 0.f, a1 = 0.f, a2 = 0.f, a3 = 0.f, a4 = 0.f;
#pragma unroll
  for (int it = 0; it < 7; ++it) {
    int i = tid + it * 1024;
    if (i < NPAIR) {
      float v = ws[OFF_P + i];
      if (i < P_C0)      a0 += v;
      else if (i < P_C1) a1 += v;
      else if (i < P_C2) a2 += v;
      else if (i < P_C3) a3 += v;
      else               a4 += v;
    }
  }
  a0 = wave_sum(a0); a1 = wave_sum(a1); a2 = wave_sum(a2);
  a3 = wave_sum(a3); a4 = wave_sum(a4);
  __shared__ float r5[16][5];
  __shared__ float slse[5];
  if (lane == 0) { r5[wv][0] = a0; r5[wv][1] = a1; r5[wv][2] = a2; r5[wv][3] = a3; r5[wv][4] = a4; }
  __syncthreads();
  if (tid < 5) {
    float s = 0.f;
#pragma unroll
    for (int w = 0; w < 16; ++w) s += r5[w][tid];
    slse[tid] = logf(s);
  }
  __syncthreads();
  const float lse0 = slse[0], lse1 = slse[1], lse2 = slse[2], lse3 = slse[3], lse4 = slse[4];
  const float g0 = ws[10000] - lse0, g1 = ws[10001] - lse0;
  const float g2 = ws[10002] - lse0, g3 = ws[10003] - lse0;
  float s = 0.f;
#pragma unroll
  for (int it = 0; it < 4; ++it) {
    int e = sg[it];
    float lseS = (e == 0) ? lse0 : (e == 1) ? lse1 : (e == 2) ? lse2 : (e == 3) ? lse3 : lse4;
    float gS   = (e == 0) ? 0.f  : (e == 1) ? g0   : (e == 2) ? g1   : (e == 3) ? g2   : g3;
    s += tv[it] - lseS + gS;
  }
  s = wave_sum(s);
  if (lane == 0) r5[wv][0] = s;
  __syncthreads();
  if (tid == 0) {
    float tot = 0.f;
#pragma unroll
    for (int w = 0; w < 16; ++w) tot += r5[w][0];
    out[0] = -tot * (1.f / 4096.f);
  }
}

extern "C" void kernel_launch(void* const* d_in, const int* in_sizes, int n_in,
                              void* d_out, int out_size, void* d_ws, size_t ws_size,
                              hipStream_t stream) {
  const float* feat    = (const float*)d_in[0];
  const int*   targets = (const int*)d_in[1];
  const float* head_w  = (const float*)d_in[2];
  const float* t0p = (const float*)d_in[3];
  const float* t0w = (const float*)d_in[4];
  const float* t1p = (const float*)d_in[5];
  const float* t1w = (const float*)d_in[6];
  const float* t2p = (const float*)d_in[7];
  const float* t2w = (const float*)d_in[8];
  const float* t3p = (const float*)d_in[9];
  const float* t3w = (const float*)d_in[10];
  float* ws  = (float*)d_ws;
  float* out = (float*)d_out;

  proj_kernel<<<240, 256, 0, stream>>>(feat, t0p, t1p, t2p, t3p, ws);
  main_kernel<<<NBLK, 256, 0, stream>>>(feat, head_w, t0w, t1w, t2w, t3w, ws);
  finalize_kernel<<<1, 1024, 0, stream>>>(targets, ws, out);
}

// Round 7
// 157.172 us; speedup vs baseline: 3.8299x; 1.0039x over previous
//
#include <hip/hip_runtime.h>
#include <math.h>

// ---------------- workspace layout (float offsets) ----------------
#define NHEAD     10004
#define OFF_HEAD  0        // 10004 head logits
#define OFF_H0    10004    // 960 projected floats (h0|h1|h2|h3 contiguous)
#define OFF_C0    10964    // 10000 cluster-0 logits
#define OFF_C1    20964    // 20000
#define OFF_C2    40964    // 40000
#define OFF_C3    80964    // 20000
#define OFF_P     100964   // per-pair exp partials (NPAIR floats)

// ---- paired 16KB units (contiguous, never cross a segment) ----
// head pairs [0,2501):    2501*4  = 10004 rows exact
// c0   pairs [2501,3751): 1250*8  = 10000 exact
// c1   pairs [3751,5001): 1250*16 = 20000 exact
// c2   pairs [5001,6251): 1250*32 = 40000 exact
// c3   pairs [6251,6564): 313*64  = 20032 (last pair half-valid)
#define P_C0   2501
#define P_C1   3751
#define P_C2   5001
#define P_C3   6251
#define NPAIR  6564
#define HALFW  3282        // waves; wave w handles pairs {w, w+HALFW}
#define NBLK   821         // 821*4 = 3284 waves (last 2 idle)

__device__ __forceinline__ float wave_sum(float v) {
  v += __shfl_xor(v, 32, 64);
  v += __shfl_xor(v, 16, 64);
  v += __shfl_xor(v, 8, 64);
  v += __shfl_xor(v, 4, 64);
  v += __shfl_xor(v, 2, 64);
  v += __shfl_xor(v, 1, 64);
  return v;
}

__device__ __forceinline__ float dot4(float4 a, float4 c) {
  return a.x * c.x + a.y * c.y + a.z * c.z + a.w * c.w;
}

// Merge two row-partials across xor-distance s (row bits -> lane bits).
__device__ __forceinline__ float mrg(float a, float b, int s, int lane) {
  float as = __shfl_xor(a, s, 64);
  float bs = __shfl_xor(b, s, 64);
  return (lane & s) ? (b + bs) : (a + as);
}

// Kernel A: 960 projection rows, 1 row/wave.
__global__ __launch_bounds__(256) void proj_kernel(
    const float* __restrict__ feat,
    const float* __restrict__ p0, const float* __restrict__ p1,
    const float* __restrict__ p2, const float* __restrict__ p3,
    float* __restrict__ ws) {
  __shared__ __align__(16) float sf[1024];
  ((float4*)sf)[threadIdx.x] = ((const float4*)feat)[threadIdx.x];
  __syncthreads();
  const float4* sf4 = (const float4*)sf;
  const int lane = threadIdx.x & 63;
  const int pr = blockIdx.x * 4 + (threadIdx.x >> 6);  // 0..959
  const float* src;
  if (pr < 512)      src = p0 + (size_t)pr * 1024;
  else if (pr < 768) src = p1 + (size_t)(pr - 512) * 1024;
  else if (pr < 896) src = p2 + (size_t)(pr - 768) * 1024;
  else               src = p3 + (size_t)(pr - 896) * 1024;
  const float4* src4 = (const float4*)src;
  float4 ld[4];
#pragma unroll
  for (int j = 0; j < 4; ++j) ld[j] = src4[lane + j * 64];
  float acc = 0.f;
#pragma unroll
  for (int j = 0; j < 4; ++j) acc += dot4(ld[j], sf4[lane + j * 64]);
  acc = wave_sum(acc);
  if (lane == 0) ws[NHEAD + pr] = acc;
}

// Segment-independent pair base: every pair is one contiguous 1024-float4
// chunk; only the base pointer differs.
__device__ __forceinline__ const float4* pair_base(
    int w, const float* __restrict__ head_w, const float* __restrict__ w0,
    const float* __restrict__ w1, const float* __restrict__ w2,
    const float* __restrict__ w3) {
  if (w < P_C0) return (const float4*)head_w + (size_t)w * 1024;
  if (w < P_C1) return (const float4*)w0 + (size_t)(w - P_C0) * 1024;
  if (w < P_C2) return (const float4*)w1 + (size_t)(w - P_C1) * 1024;
  if (w < P_C3) return (const float4*)w2 + (size_t)(w - P_C2) * 1024;
  return (const float4*)w3 + (size_t)(w - P_C3) * 1024;
}

// A-set computes: pairs [0, HALFW) are ONLY head or c0.
#define COMPUTE_A(W, LD, ESUM) do {                                         \
  if ((W) < P_C0) {                   /* head: 4 rows, D=1024 */            \
    const float4* sf4 = (const float4*)sh;                                  \
    float a0 = 0.f, a1 = 0.f, a2 = 0.f, a3 = 0.f;                           \
    _Pragma("unroll")                                                       \
    for (int j = 0; j < 4; ++j) {                                           \
      float4 f = sf4[lane + j * 64];                                        \
      a0 += dot4(LD[j], f);  a1 += dot4(LD[4 + j], f);                      \
      a2 += dot4(LD[8 + j], f); a3 += dot4(LD[12 + j], f);                  \
    }                                                                       \
    float u0 = mrg(a0, a1, 1, lane), u1 = mrg(a2, a3, 1, lane);             \
    float y = mrg(u0, u1, 2, lane);                                         \
    y += __shfl_xor(y, 4, 64);                                              \
    y += __shfl_xor(y, 8, 64);                                              \
    y += __shfl_xor(y, 16, 64);                                             \
    y += __shfl_xor(y, 32, 64);                                             \
    if (lane < 4) ws[OFF_HEAD + (W) * 4 + lane] = y;                        \
    float ev = expf(y);                                                     \
    ev += __shfl_xor(ev, 1, 64);                                            \
    ev += __shfl_xor(ev, 2, 64);                                            \
    ESUM = ev;                                                              \
  } else {                            /* c0: 8 rows, h=512 */               \
    const float4* h4 = (const float4*)(sh + 1024);                          \
    const float4 cv0 = h4[lane], cv1 = h4[lane + 64];                       \
    const int r0 = ((W) - P_C0) * 8;                                        \
    float a[8];                                                             \
    _Pragma("unroll")                                                       \
    for (int k = 0; k < 8; ++k)                                             \
      a[k] = dot4(LD[2 * k], cv0) + dot4(LD[2 * k + 1], cv1);               \
    float u[4];                                                             \
    _Pragma("unroll")                                                       \
    for (int m = 0; m < 4; ++m) u[m] = mrg(a[2 * m], a[2 * m + 1], 1, lane);\
    float v0 = mrg(u[0], u[1], 2, lane), v1 = mrg(u[2], u[3], 2, lane);     \
    float y = mrg(v0, v1, 4, lane);     /* row = lane&7 */                  \
    y += __shfl_xor(y, 8, 64);                                              \
    y += __shfl_xor(y, 16, 64);                                             \
    y += __shfl_xor(y, 32, 64);                                             \
    if (lane < 8) ws[OFF_C0 + r0 + lane] = y;                               \
    float ev = expf(y);                                                     \
    ev += __shfl_xor(ev, 1, 64);                                            \
    ev += __shfl_xor(ev, 2, 64);                                            \
    ev += __shfl_xor(ev, 4, 64);                                            \
    ESUM = ev;                                                              \
  }                                                                         \
} while (0)

// B-set computes: pairs [HALFW, NPAIR) are ONLY c0/c1/c2/c3.
#define COMPUTE_B(W, LD, ESUM) do {                                         \
  if ((W) < P_C1) {                   /* c0: 8 rows, h=512 */               \
    const float4* h4 = (const float4*)(sh + 1024);                          \
    const float4 cv0 = h4[lane], cv1 = h4[lane + 64];                       \
    const int r0 = ((W) - P_C0) * 8;                                        \
    float a[8];                                                             \
    _Pragma("unroll")                                                       \
    for (int k = 0; k < 8; ++k)                                             \
      a[k] = dot4(LD[2 * k], cv0) + dot4(LD[2 * k + 1], cv1);               \
    float u[4];                                                             \
    _Pragma("unroll")                                                       \
    for (int m = 0; m < 4; ++m) u[m] = mrg(a[2 * m], a[2 * m + 1], 1, lane);\
    float v0 = mrg(u[0], u[1], 2, lane), v1 = mrg(u[2], u[3], 2, lane);     \
    float y = mrg(v0, v1, 4, lane);                                         \
    y += __shfl_xor(y, 8, 64);                                              \
    y += __shfl_xor(y, 16, 64);                                             \
    y += __shfl_xor(y, 32, 64);                                             \
    if (lane < 8) ws[OFF_C0 + r0 + lane] = y;                               \
    float ev = expf(y);                                                     \
    ev += __shfl_xor(ev, 1, 64);                                            \
    ev += __shfl_xor(ev, 2, 64);                                            \
    ev += __shfl_xor(ev, 4, 64);                                            \
    ESUM = ev;                                                              \
  } else if ((W) < P_C2) {            /* c1: 16 rows, h=256 */              \
    const float4 cv = ((const float4*)(sh + 1536))[lane];                   \
    const int r0 = ((W) - P_C1) * 16;                                       \
    float a[16];                                                            \
    _Pragma("unroll")                                                       \
    for (int k = 0; k < 16; ++k) a[k] = dot4(LD[k], cv);                    \
    float u[8];                                                             \
    _Pragma("unroll")                                                       \
    for (int m = 0; m < 8; ++m) u[m] = mrg(a[2 * m], a[2 * m + 1], 1, lane);\
    float v2[4];                                                            \
    _Pragma("unroll")                                                       \
    for (int m = 0; m < 4; ++m) v2[m] = mrg(u[2 * m], u[2 * m + 1], 2, lane);\
    float w2r[2];                                                           \
    _Pragma("unroll")                                                       \
    for (int m = 0; m < 2; ++m) w2r[m] = mrg(v2[2 * m], v2[2 * m + 1], 4, lane);\
    float y = mrg(w2r[0], w2r[1], 8, lane);  /* row = lane&15 */            \
    y += __shfl_xor(y, 16, 64);                                             \
    y += __shfl_xor(y, 32, 64);                                             \
    if (lane < 16) ws[OFF_C1 + r0 + lane] = y;                              \
    float ev = expf(y);                                                     \
    ev += __shfl_xor(ev, 1, 64);                                            \
    ev += __shfl_xor(ev, 2, 64);                                            \
    ev += __shfl_xor(ev, 4, 64);                                            \
    ev += __shfl_xor(ev, 8, 64);                                            \
    ESUM = ev;                                                              \
  } else if ((W) < P_C3) {            /* c2: 32 rows, h=128 */              \
    const float4 cv = ((const float4*)(sh + 1792))[lane & 31];              \
    const int r0 = ((W) - P_C2) * 32;                                       \
    float a[16];                                                            \
    _Pragma("unroll")                                                       \
    for (int p = 0; p < 16; ++p) a[p] = dot4(LD[p], cv);                    \
    float u[8];                                                             \
    _Pragma("unroll")                                                       \
    for (int m = 0; m < 8; ++m) u[m] = mrg(a[2 * m], a[2 * m + 1], 1, lane);\
    float v2[4];                                                            \
    _Pragma("unroll")                                                       \
    for (int m = 0; m < 4; ++m) v2[m] = mrg(u[2 * m], u[2 * m + 1], 2, lane);\
    float w2r[2];                                                           \
    _Pragma("unroll")                                                       \
    for (int m = 0; m < 2; ++m) w2r[m] = mrg(v2[2 * m], v2[2 * m + 1], 4, lane);\
    float y = mrg(w2r[0], w2r[1], 8, lane);  /* p = lane&15 */              \
    y += __shfl_xor(y, 16, 64);       /* full 32-lane row sum (dup) */      \
    int rr = 2 * (lane & 15) + (lane >> 5);                                 \
    if (!(lane & 16)) ws[OFF_C2 + r0 + rr] = y;                             \
    float ev = expf(y);                                                     \
    ev += __shfl_xor(ev, 1, 64);                                            \
    ev += __shfl_xor(ev, 2, 64);                                            \
    ev += __shfl_xor(ev, 4, 64);                                            \
    ev += __shfl_xor(ev, 8, 64);                                            \
    ev += __shfl_xor(ev, 32, 64);                                           \
    ESUM = ev;                                                              \
  } else {                            /* c3: 64 rows, h=64 */               \
    const float4 cv = ((const float4*)(sh + 1920))[lane & 15];              \
    const int r0 = ((W) - P_C3) * 64;                                       \
    float a[16];                                                            \
    _Pragma("unroll")                                                       \
    for (int p = 0; p < 16; ++p) a[p] = dot4(LD[p], cv);                    \
    float u[8];                                                             \
    _Pragma("unroll")                                                       \
    for (int m = 0; m < 8; ++m) u[m] = mrg(a[2 * m], a[2 * m + 1], 1, lane);\
    float v2[4];                                                            \
    _Pragma("unroll")                                                       \
    for (int m = 0; m < 4; ++m) v2[m] = mrg(u[2 * m], u[2 * m + 1], 2, lane);\
    float w2r[2];                                                           \
    _Pragma("unroll")                                                       \
    for (int m = 0; m < 2; ++m) w2r[m] = mrg(v2[2 * m], v2[2 * m + 1], 4, lane);\
    float y = mrg(w2r[0], w2r[1], 8, lane);  /* full row sum */             \
    int rr = 4 * (lane & 15) + (lane >> 4);  /* all 64 lanes distinct */    \
    bool valid = (r0 + rr) < 20000;                                         \
    if (valid) ws[OFF_C3 + r0 + rr] = y;                                    \
    float ev = valid ? expf(y) : 0.f;                                       \
    ESUM = wave_sum(ev);                                                    \
  }                                                                         \
} while (0)

// Kernel B: 821 blocks, 2-deep pipelined: each wave issues ALL 32 loads for
// pairs {w, w+3282} up front (pair loads are segment-independent), then
// computes A while B's loads are still in flight. ldA/ldB in one scope,
// constant indices, macro computes (no pointer params) — scratch-proof.
// (256,2): 256-VGPR cap for ~190 peak live. sched_barrier stops the
// scheduler sinking B's loads below computeA.
__global__ __launch_bounds__(256, 2) void main_kernel(
    const float* __restrict__ feat, const float* __restrict__ head_w,
    const float* __restrict__ w0, const float* __restrict__ w1,
    const float* __restrict__ w2, const float* __restrict__ w3,
    float* __restrict__ ws) {
  __shared__ __align__(16) float sh[1984];  // feat[1024] | proj[960]
  const int t = threadIdx.x;
  ((float4*)sh)[t] = ((const float4*)feat)[t];
  if (t < 240) ((float4*)(sh + 1024))[t] = ((const float4*)(ws + OFF_H0))[t];
  __syncthreads();
  const int lane = t & 63;
  const int wid = blockIdx.x * 4 + (t >> 6);
  if (wid >= HALFW) return;  // wave-uniform; only last block's tail waves

  const int wA = wid, wB = wid + HALFW;
  const float4* bA = pair_base(wA, head_w, w0, w1, w2, w3);
  const float4* bB = pair_base(wB, head_w, w0, w1, w2, w3);
  const float4* bB2 = bB + ((wB == NPAIR - 1) ? 0 : 512);  // c3 OOB clamp

  float4 ldA[16], ldB[16];
#pragma unroll
  for (int j = 0; j < 8; ++j) ldA[j] = bA[j * 64 + lane];
#pragma unroll
  for (int j = 0; j < 8; ++j) ldA[8 + j] = bA[512 + j * 64 + lane];
#pragma unroll
  for (int j = 0; j < 8; ++j) ldB[j] = bB[j * 64 + lane];
#pragma unroll
  for (int j = 0; j < 8; ++j) ldB[8 + j] = bB2[j * 64 + lane];
  __builtin_amdgcn_sched_barrier(0);

  float esA, esB;
  COMPUTE_A(wA, ldA, esA);
  COMPUTE_B(wB, ldB, esB);
  if (lane == 0) { ws[OFF_P + wA] = esA; ws[OFF_P + wB] = esB; }
}

// Kernel C: single 1024-thread block. Gathers issued branchlessly at entry
// (addr = t + (t>=10000)*964 by layout), overlapping the partial reduction.
__global__ __launch_bounds__(1024) void finalize_kernel(
    const int* __restrict__ targets, float* __restrict__ ws,
    float* __restrict__ out) {
  const int tid = threadIdx.x;
  const int wv = tid >> 6, lane = tid & 63;
  float tv[4]; int sg[4];
#pragma unroll
  for (int it = 0; it < 4; ++it) {
    int tgt = targets[tid + it * 1024];
    int addr = tgt + ((tgt >= 10000) ? 964 : 0);
    tv[it] = ws[addr];
    sg[it] = (tgt >= 10000) + (tgt >= 20000) + (tgt >= 40000) + (tgt >= 80000);
  }
  // segmented reduction of 6564 per-pair partials
  float a0 = 0.f, a1 = 0.f, a2 = 0.f, a3 = 0.f, a4 = 0.f;
#pragma unroll
  for (int it = 0; it < 7; ++it) {
    int i = tid + it * 1024;
    if (i < NPAIR) {
      float v = ws[OFF_P + i];
      if (i < P_C0)      a0 += v;
      else if (i < P_C1) a1 += v;
      else if (i < P_C2) a2 += v;
      else if (i < P_C3) a3 += v;
      else               a4 += v;
    }
  }
  a0 = wave_sum(a0); a1 = wave_sum(a1); a2 = wave_sum(a2);
  a3 = wave_sum(a3); a4 = wave_sum(a4);
  __shared__ float r5[16][5];
  __shared__ float slse[5];
  if (lane == 0) { r5[wv][0] = a0; r5[wv][1] = a1; r5[wv][2] = a2; r5[wv][3] = a3; r5[wv][4] = a4; }
  __syncthreads();
  if (tid < 5) {
    float s = 0.f;
#pragma unroll
    for (int w = 0; w < 16; ++w) s += r5[w][tid];
    slse[tid] = logf(s);
  }
  __syncthreads();
  const float lse0 = slse[0], lse1 = slse[1], lse2 = slse[2], lse3 = slse[3], lse4 = slse[4];
  const float g0 = ws[10000] - lse0, g1 = ws[10001] - lse0;
  const float g2 = ws[10002] - lse0, g3 = ws[10003] - lse0;
  float s = 0.f;
#pragma unroll
  for (int it = 0; it < 4; ++it) {
    int e = sg[it];
    float lseS = (e == 0) ? lse0 : (e == 1) ? lse1 : (e == 2) ? lse2 : (e == 3) ? lse3 : lse4;
    float gS   = (e == 0) ? 0.f  : (e == 1) ? g0   : (e == 2) ? g1   : (e == 3) ? g2   : g3;
    s += tv[it] - lseS + gS;
  }
  s = wave_sum(s);
  if (lane == 0) r5[wv][0] = s;
  __syncthreads();
  if (tid == 0) {
    float tot = 0.f;
#pragma unroll
    for (int w = 0; w < 16; ++w) tot += r5[w][0];
    out[0] = -tot * (1.f / 4096.f);
  }
}

extern "C" void kernel_launch(void* const* d_in, const int* in_sizes, int n_in,
                              void* d_out, int out_size, void* d_ws, size_t ws_size,
                              hipStream_t stream) {
  const float* feat    = (const float*)d_in[0];
  const int*   targets = (const int*)d_in[1];
  const float* head_w  = (const float*)d_in[2];
  const float* t0p = (const float*)d_in[3];
  const float* t0w = (const float*)d_in[4];
  const float* t1p = (const float*)d_in[5];
  const float* t1w = (const float*)d_in[6];
  const float* t2p = (const float*)d_in[7];
  const float* t2w = (const float*)d_in[8];
  const float* t3p = (const float*)d_in[9];
  const float* t3w = (const float*)d_in[10];
  float* ws  = (float*)d_ws;
  float* out = (float*)d_out;

  proj_kernel<<<240, 256, 0, stream>>>(feat, t0p, t1p, t2p, t3p, ws);
  main_kernel<<<NBLK, 256, 0, stream>>>(feat, head_w, t0w, t1w, t2w, t3w, ws);
  finalize_kernel<<<1, 1024, 0, stream>>>(targets, ws, out);
}